// Round 1
// baseline (15994.826 us; speedup 1.0000x reference)
//
#include <hip/hip_runtime.h>
#include <cmath>

static inline int cdiv(long a, int b){ return (int)((a + b - 1) / b); }

__device__ __forceinline__ float lrelu(float x){ return x > 0.f ? x : 0.2f * x; }

__device__ __forceinline__ void atomicMaxF32(float* addr, float val){
  int* ia = reinterpret_cast<int*>(addr);
  int old = *ia;
  while (__int_as_float(old) < val) {
    int assumed = old;
    old = atomicCAS(ia, assumed, __float_as_int(val));
    if (old == assumed) break;
  }
}

__global__ void fill_f32(float* __restrict__ p, float v, int n){
  int i = blockIdx.x * blockDim.x + threadIdx.x;
  if (i < n) p[i] = v;
}

// degree + scatter-sum of edge_attr by dst (for self-loop fill_value='mean')
__global__ void deg_meansum_kernel(const int* __restrict__ ei, int E,
                                   const float* __restrict__ eattr,
                                   float* __restrict__ deg, float* __restrict__ msum){
  int e = blockIdx.x * blockDim.x + threadIdx.x;
  if (e >= E) return;
  int d = ei[E + e];
  atomicAdd(&deg[d], 1.f);
  const float4* ea = reinterpret_cast<const float4*>(eattr + (size_t)e * 8);
  float4 a0 = ea[0], a1 = ea[1];
  float* m = msum + (size_t)d * 8;
  atomicAdd(m + 0, a0.x); atomicAdd(m + 1, a0.y);
  atomicAdd(m + 2, a0.z); atomicAdd(m + 3, a0.w);
  atomicAdd(m + 4, a1.x); atomicAdd(m + 5, a1.y);
  atomicAdd(m + 6, a1.z); atomicAdd(m + 7, a1.w);
}

__global__ void mean_div_kernel(float* __restrict__ msum, const float* __restrict__ deg, int n){
  int i = blockIdx.x * blockDim.x + threadIdx.x;
  if (i >= n * 8) return;
  msum[i] /= fmaxf(deg[i >> 3], 1.f);
}

// wevec[d*4+h] = sum_c We1[d, h*8+c] * a_e1[h,c]  (folds edge transform to 8x4)
__global__ void wevec_kernel(const float* __restrict__ We, const float* __restrict__ ae,
                             float* __restrict__ wev){
  int i = threadIdx.x;
  if (i >= 32) return;
  int d = i >> 2, h = i & 3;
  float acc = 0.f;
  #pragma unroll
  for (int c = 0; c < 8; ++c) acc = fmaf(We[d * 32 + h * 8 + c], ae[h * 8 + c], acc);
  wev[d * 4 + h] = acc;
}

// out[n, M] = A[n, K] @ W[K, M] ; W staged in LDS, one output per thread
template<int K, int M>
__global__ void gemm_kernel(const float* __restrict__ A, const float* __restrict__ W,
                            float* __restrict__ out, int n){
  __shared__ float Ws[K * M];
  for (int i = threadIdx.x; i < K * M; i += blockDim.x) Ws[i] = W[i];
  __syncthreads();
  constexpr int ROWS = 256 / M;
  int row = blockIdx.x * ROWS + (int)threadIdx.x / M;
  int col = (int)threadIdx.x % M;
  if (row >= n) return;
  const float* a = A + (size_t)row * K;
  float acc = 0.f;
  #pragma unroll
  for (int k = 0; k < K; ++k) acc = fmaf(a[k], Ws[k * M + col], acc);
  out[(size_t)row * M + col] = acc;
}

// per (node, head) attention pre-scores
template<int M, int C>
__global__ void score_kernel(const float* __restrict__ xh, const float* __restrict__ asrc,
                             const float* __restrict__ adst,
                             float* __restrict__ ss, float* __restrict__ sd, int n){
  int i = blockIdx.x * blockDim.x + threadIdx.x;
  if (i >= n * 4) return;
  int node = i >> 2, h = i & 3;
  const float* xr = xh + (size_t)node * M + h * C;
  float s = 0.f, d = 0.f;
  #pragma unroll
  for (int c = 0; c < C; ++c) {
    s = fmaf(xr[c], asrc[h * C + c], s);
    d = fmaf(xr[c], adst[h * C + c], d);
  }
  ss[i] = s; sd[i] = d;
}

template<bool EDGE>
__device__ __forceinline__ void edge_alpha(int e, int E, const int* __restrict__ ei,
    const float* __restrict__ eattr, const float* __restrict__ mattr,
    const float* __restrict__ wev, const float* __restrict__ ssrc,
    const float* __restrict__ sdst, int& s, int& d, float (&al)[4]){
  const float* ea;
  if (e < E) { s = ei[e]; d = ei[E + e]; ea = eattr + (size_t)e * 8; }
  else       { s = e - E; d = s;          ea = mattr + (size_t)(e - E) * 8; }
  float esc[4] = {0.f, 0.f, 0.f, 0.f};
  if (EDGE) {
    const float4* e4 = reinterpret_cast<const float4*>(ea);
    float4 a0 = e4[0], a1 = e4[1];
    float av[8] = {a0.x, a0.y, a0.z, a0.w, a1.x, a1.y, a1.z, a1.w};
    #pragma unroll
    for (int k = 0; k < 8; ++k)
      #pragma unroll
      for (int h = 0; h < 4; ++h) esc[h] = fmaf(av[k], wev[k * 4 + h], esc[h]);
  }
  #pragma unroll
  for (int h = 0; h < 4; ++h)
    al[h] = lrelu(ssrc[s * 4 + h] + sdst[d * 4 + h] + esc[h]);
}

template<bool EDGE>
__global__ void alpha_max_kernel(const int* __restrict__ ei, int E, int EA,
    const float* __restrict__ eattr, const float* __restrict__ mattr,
    const float* __restrict__ wev, const float* __restrict__ ssrc,
    const float* __restrict__ sdst, float* __restrict__ amax){
  int e = blockIdx.x * blockDim.x + threadIdx.x;
  if (e >= EA) return;
  int s, d; float al[4];
  edge_alpha<EDGE>(e, E, ei, eattr, mattr, wev, ssrc, sdst, s, d, al);
  #pragma unroll
  for (int h = 0; h < 4; ++h) atomicMaxF32(&amax[d * 4 + h], al[h]);
}

template<bool EDGE, int C>
__global__ void agg_kernel(const int* __restrict__ ei, int E, int EA,
    const float* __restrict__ eattr, const float* __restrict__ mattr,
    const float* __restrict__ wev, const float* __restrict__ ssrc,
    const float* __restrict__ sdst, const float* __restrict__ amax,
    const float* __restrict__ xh, float* __restrict__ denom, float* __restrict__ agg){
  int e = blockIdx.x * blockDim.x + threadIdx.x;
  if (e >= EA) return;
  int s, d; float al[4];
  edge_alpha<EDGE>(e, E, ei, eattr, mattr, wev, ssrc, sdst, s, d, al);
  #pragma unroll
  for (int h = 0; h < 4; ++h) {
    float w = expf(al[h] - amax[d * 4 + h]);
    atomicAdd(&denom[d * 4 + h], w);
    const float* xs = xh + (size_t)s * (4 * C) + h * C;
    float* ag = agg + (size_t)d * (4 * C) + h * C;
    #pragma unroll
    for (int c = 0; c < C; ++c) atomicAdd(&ag[c], w * xs[c]);
  }
}

// layer1: concat heads, + bias, ELU
__global__ void finalize1_kernel(const float* __restrict__ agg, const float* __restrict__ denom,
                                 const float* __restrict__ b, float* __restrict__ h1, int n){
  int i = blockIdx.x * blockDim.x + threadIdx.x;
  if (i >= n * 32) return;
  int node = i >> 5, j = i & 31, h = j >> 3;
  float v = agg[i] / (denom[node * 4 + h] + 1e-16f) + b[j];
  h1[i] = v > 0.f ? v : expm1f(v);
}

// layer2: mean over heads, + bias, ELU
__global__ void finalize2_kernel(const float* __restrict__ agg, const float* __restrict__ denom,
                                 const float* __restrict__ b, float* __restrict__ h2, int n){
  int i = blockIdx.x * blockDim.x + threadIdx.x;
  if (i >= n * 8) return;
  int node = i >> 3, c = i & 7;
  float acc = 0.f;
  #pragma unroll
  for (int h = 0; h < 4; ++h)
    acc += agg[(size_t)node * 32 + h * 8 + c] / (denom[node * 4 + h] + 1e-16f);
  float v = acc * 0.25f + b[c];
  h2[i] = v > 0.f ? v : expm1f(v);
}

// layer3: mean over heads, + bias (no activation)
__global__ void finalize3_kernel(const float* __restrict__ agg, const float* __restrict__ denom,
                                 const float* __restrict__ b, float* __restrict__ out, int n){
  int i = blockIdx.x * blockDim.x + threadIdx.x;
  if (i >= n) return;
  float acc = 0.f;
  #pragma unroll
  for (int h = 0; h < 4; ++h)
    acc += agg[(size_t)i * 4 + h] / (denom[i * 4 + h] + 1e-16f);
  out[i] = acc * 0.25f + b[0];
}

extern "C" void kernel_launch(void* const* d_in, const int* in_sizes, int n_in,
                              void* d_out, int out_size, void* d_ws, size_t ws_size,
                              hipStream_t stream){
  const float* x     = (const float*)d_in[0];
  const float* eattr = (const float*)d_in[1];
  const int*   ei    = (const int*)d_in[2];
  const float* W1  = (const float*)d_in[3];
  const float* as1 = (const float*)d_in[4];
  const float* ad1 = (const float*)d_in[5];
  const float* We1 = (const float*)d_in[6];
  const float* ae1 = (const float*)d_in[7];
  const float* b1  = (const float*)d_in[8];
  const float* W2  = (const float*)d_in[9];
  const float* as2 = (const float*)d_in[10];
  const float* ad2 = (const float*)d_in[11];
  const float* b2  = (const float*)d_in[12];
  const float* W3  = (const float*)d_in[13];
  const float* as3 = (const float*)d_in[14];
  const float* ad3 = (const float*)d_in[15];
  const float* b3  = (const float*)d_in[16];

  const int N  = in_sizes[0] / 128;
  const int E  = in_sizes[2] / 2;
  const int EA = E + N;

  float* p = (float*)d_ws;
  float* xh    = p; p += (size_t)N * 32;
  float* sS    = p; p += (size_t)N * 4;
  float* sD    = p; p += (size_t)N * 4;
  float* amax  = p; p += (size_t)N * 4;
  float* denom = p; p += (size_t)N * 4;   // denom then agg: contiguous for memset
  float* agg   = p; p += (size_t)N * 32;
  float* h1    = p; p += (size_t)N * 32;
  float* h2    = p; p += (size_t)N * 8;
  float* mattr = p; p += (size_t)N * 8;   // mattr then deg: contiguous for memset
  float* deg   = p; p += (size_t)N;
  float* wev   = p; p += 32;

  const int B = 256;

  // ---- self-loop edge_attr = scatter-mean by dst ----
  hipMemsetAsync(mattr, 0, (size_t)N * 9 * sizeof(float), stream);
  deg_meansum_kernel<<<cdiv(E, B), B, 0, stream>>>(ei, E, eattr, deg, mattr);
  mean_div_kernel<<<cdiv(N * 8, B), B, 0, stream>>>(mattr, deg, N);
  wevec_kernel<<<1, 32, 0, stream>>>(We1, ae1, wev);

  // ---- layer 1: 128 -> 4x8, concat, edge features ----
  gemm_kernel<128,32><<<cdiv(N, 8), B, 0, stream>>>(x, W1, xh, N);
  score_kernel<32,8><<<cdiv(N * 4, B), B, 0, stream>>>(xh, as1, ad1, sS, sD, N);
  fill_f32<<<cdiv(N * 4, B), B, 0, stream>>>(amax, -INFINITY, N * 4);
  hipMemsetAsync(denom, 0, (size_t)N * 36 * sizeof(float), stream);
  alpha_max_kernel<true><<<cdiv(EA, B), B, 0, stream>>>(ei, E, EA, eattr, mattr, wev, sS, sD, amax);
  agg_kernel<true,8><<<cdiv(EA, B), B, 0, stream>>>(ei, E, EA, eattr, mattr, wev, sS, sD, amax, xh, denom, agg);
  finalize1_kernel<<<cdiv(N * 32, B), B, 0, stream>>>(agg, denom, b1, h1, N);

  // ---- layer 2: 32 -> 4x8, mean over heads ----
  gemm_kernel<32,32><<<cdiv(N, 8), B, 0, stream>>>(h1, W2, xh, N);
  score_kernel<32,8><<<cdiv(N * 4, B), B, 0, stream>>>(xh, as2, ad2, sS, sD, N);
  fill_f32<<<cdiv(N * 4, B), B, 0, stream>>>(amax, -INFINITY, N * 4);
  hipMemsetAsync(denom, 0, (size_t)N * 36 * sizeof(float), stream);
  alpha_max_kernel<false><<<cdiv(EA, B), B, 0, stream>>>(ei, E, EA, eattr, mattr, wev, sS, sD, amax);
  agg_kernel<false,8><<<cdiv(EA, B), B, 0, stream>>>(ei, E, EA, eattr, mattr, wev, sS, sD, amax, xh, denom, agg);
  finalize2_kernel<<<cdiv(N * 8, B), B, 0, stream>>>(agg, denom, b2, h2, N);

  // ---- layer 3: 8 -> 4x1, mean over heads ----
  gemm_kernel<8,4><<<cdiv(N, 64), B, 0, stream>>>(h2, W3, xh, N);
  score_kernel<4,1><<<cdiv(N * 4, B), B, 0, stream>>>(xh, as3, ad3, sS, sD, N);
  fill_f32<<<cdiv(N * 4, B), B, 0, stream>>>(amax, -INFINITY, N * 4);
  hipMemsetAsync(denom, 0, (size_t)N * 8 * sizeof(float), stream);  // denom + agg[0:N*4]
  alpha_max_kernel<false><<<cdiv(EA, B), B, 0, stream>>>(ei, E, EA, eattr, mattr, wev, sS, sD, amax);
  agg_kernel<false,1><<<cdiv(EA, B), B, 0, stream>>>(ei, E, EA, eattr, mattr, wev, sS, sD, amax, xh, denom, agg);
  finalize3_kernel<<<cdiv(N, B), B, 0, stream>>>(agg, denom, b3, (float*)d_out, N);
}

// Round 2
// 881.021 us; speedup vs baseline: 18.1549x; 18.1549x over previous
//
#include <hip/hip_runtime.h>
#include <cmath>

static inline int cdiv(long a, int b){ return (int)((a + b - 1) / b); }

__device__ __forceinline__ float lrelu(float x){ return x > 0.f ? x : 0.2f * x; }
__device__ __forceinline__ float elu1(float x){ return x > 0.f ? x : expm1f(x); }

// compiler-level fence: keep LDS writes (phase1) before LDS reads (phase2)
// within the same wave; HW DS pipe is in-order per wave.
#define WAVE_FENCE() do { asm volatile("" ::: "memory"); __builtin_amdgcn_sched_barrier(0); } while(0)

// ---------------- CSR build ----------------

__global__ void hist_kernel(const int* __restrict__ ei, int E, int* __restrict__ cnt){
  int e = blockIdx.x * blockDim.x + threadIdx.x;
  if (e < E) atomicAdd(&cnt[ei[E + e]], 1);
}

// single-block exclusive scan of (cnt[i]+1); row_start[N]=total; cursor=row_start+1
__global__ void scan_kernel(const int* __restrict__ cnt, int* __restrict__ row_start,
                            int* __restrict__ cursor, int n){
  __shared__ int s[1024];
  int t = threadIdx.x;
  int carry = 0;
  for (int base = 0; base < n; base += 1024){
    int v = (base + t < n) ? cnt[base + t] + 1 : 0;
    s[t] = v; __syncthreads();
    for (int off = 1; off < 1024; off <<= 1){
      int u = (t >= off) ? s[t - off] : 0;
      __syncthreads();
      s[t] += u;
      __syncthreads();
    }
    int excl = s[t] - v;
    if (base + t < n){ row_start[base + t] = carry + excl; cursor[base + t] = carry + excl + 1; }
    carry += s[1023];
    __syncthreads();
  }
  if (t == 0) row_start[n] = carry;
}

// real edges go to positions [row_start[d]+1, row_end); slot row_start[d] reserved for self-loop
__global__ void scatter_kernel(const int* __restrict__ ei, int E, int* __restrict__ cursor,
                               int* __restrict__ srcs, int* __restrict__ eid){
  int e = blockIdx.x * blockDim.x + threadIdx.x;
  if (e >= E) return;
  int d = ei[E + e];
  int pos = atomicAdd(&cursor[d], 1);
  srcs[pos] = ei[e];
  eid[pos] = e;
}

// wev[d*4+h] = sum_c We1[d, h*8+c] * a_e1[h,c]
__global__ void wevec_kernel(const float* __restrict__ We, const float* __restrict__ ae,
                             float* __restrict__ wev){
  int i = threadIdx.x;
  if (i >= 32) return;
  int d = i >> 2, h = i & 3;
  float acc = 0.f;
  #pragma unroll
  for (int c = 0; c < 8; ++c) acc = fmaf(We[d * 32 + h * 8 + c], ae[h * 8 + c], acc);
  wev[d * 4 + h] = acc;
}

// per node (one wave): gather eattr of its real edges, write per-edge escore[4],
// compute mean attr -> self-loop escore at slot row_start[node]; also srcs[row_start]=node
__global__ void edge_prep_kernel(const int* __restrict__ row_start, const int* __restrict__ eid,
                                 const float* __restrict__ eattr, const float* __restrict__ wev,
                                 int* __restrict__ srcs, float* __restrict__ esc, int n){
  __shared__ float s_wev[32];
  if (threadIdx.x < 32) s_wev[threadIdx.x] = wev[threadIdx.x];
  __syncthreads();
  int wv = threadIdx.x >> 6, lane = threadIdx.x & 63;
  int node = blockIdx.x * 4 + wv;
  if (node >= n) return;
  int rs = row_start[node];
  int dr = row_start[node + 1] - rs - 1;            // real in-edges
  float asum[8] = {0,0,0,0,0,0,0,0};
  for (int base = 0; base < dr; base += 64){
    int k = base + lane;
    if (k < dr){
      int e = eid[rs + 1 + k];
      const float4* ea = (const float4*)(eattr + (size_t)e * 8);
      float4 a0 = ea[0], a1 = ea[1];
      float av[8] = {a0.x,a0.y,a0.z,a0.w,a1.x,a1.y,a1.z,a1.w};
      float e0=0,e1=0,e2=0,e3=0;
      #pragma unroll
      for (int d2 = 0; d2 < 8; ++d2){
        e0 = fmaf(av[d2], s_wev[d2*4+0], e0);
        e1 = fmaf(av[d2], s_wev[d2*4+1], e1);
        e2 = fmaf(av[d2], s_wev[d2*4+2], e2);
        e3 = fmaf(av[d2], s_wev[d2*4+3], e3);
        asum[d2] += av[d2];
      }
      *(float4*)(esc + (size_t)(rs + 1 + k) * 4) = make_float4(e0,e1,e2,e3);
    }
  }
  #pragma unroll
  for (int d2 = 0; d2 < 8; ++d2)
    for (int off = 1; off < 64; off <<= 1) asum[d2] += __shfl_xor(asum[d2], off, 64);
  float inv = 1.f / fmaxf((float)dr, 1.f);
  float e0=0,e1=0,e2=0,e3=0;
  #pragma unroll
  for (int d2 = 0; d2 < 8; ++d2){
    float m = asum[d2] * inv;
    e0 = fmaf(m, s_wev[d2*4+0], e0);
    e1 = fmaf(m, s_wev[d2*4+1], e1);
    e2 = fmaf(m, s_wev[d2*4+2], e2);
    e3 = fmaf(m, s_wev[d2*4+3], e3);
  }
  if (lane == 0){
    srcs[rs] = node;
    *(float4*)(esc + (size_t)rs * 4) = make_float4(e0,e1,e2,e3);
  }
}

// ---------------- dense per-node transforms ----------------

// out[n, M] = A[n, K] @ W[K, M] ; W staged in LDS, one output per thread
template<int K, int M>
__global__ void gemm_kernel(const float* __restrict__ A, const float* __restrict__ W,
                            float* __restrict__ out, int n){
  __shared__ float Ws[K * M];
  for (int i = threadIdx.x; i < K * M; i += blockDim.x) Ws[i] = W[i];
  __syncthreads();
  constexpr int ROWS = 256 / M;
  int row = blockIdx.x * ROWS + (int)threadIdx.x / M;
  int col = (int)threadIdx.x % M;
  if (row >= n) return;
  const float* a = A + (size_t)row * K;
  float acc = 0.f;
  #pragma unroll
  for (int k = 0; k < K; ++k) acc = fmaf(a[k], Ws[k * M + col], acc);
  out[(size_t)row * M + col] = acc;
}

// per (node, head) attention pre-scores
template<int M, int C>
__global__ void score_kernel(const float* __restrict__ xh, const float* __restrict__ asrc,
                             const float* __restrict__ adst,
                             float* __restrict__ ss, float* __restrict__ sd, int n){
  int i = blockIdx.x * blockDim.x + threadIdx.x;
  if (i >= n * 4) return;
  int node = i >> 2, h = i & 3;
  const float* xr = xh + (size_t)node * M + h * C;
  float s = 0.f, d = 0.f;
  #pragma unroll
  for (int c = 0; c < C; ++c){
    s = fmaf(xr[c], asrc[h * C + c], s);
    d = fmaf(xr[c], adst[h * C + c], d);
  }
  ss[i] = s; sd[i] = d;
}

// ---------------- CSR gather-aggregate (no atomics, no amax pass) ----------------
// MODE 0: concat heads + bias + ELU (layer1, OUT=32)
// MODE 1: mean heads + bias + ELU   (layer2, OUT=32 -> 8)
// MODE 2: mean heads + bias         (layer3, OUT=4  -> 1)
template<int C, int MODE, bool EDGE>
__global__ void gather_kernel(const int* __restrict__ row_start, const int* __restrict__ srcs,
                              const float* __restrict__ esc, const float* __restrict__ sS,
                              const float* __restrict__ sD, const float* __restrict__ xh,
                              const float* __restrict__ bias, float* __restrict__ out, int n){
  constexpr int OUT = 4 * C;
  constexpr int EPI = 64 / OUT;        // edges per phase-2 iteration
  __shared__ float4 s_w[4][64];
  __shared__ int    s_src[4][64];
  int wv = threadIdx.x >> 6, lane = threadIdx.x & 63;
  int node = blockIdx.x * 4 + wv;
  if (node >= n) return;
  int rs = row_start[node], deg = row_start[node + 1] - rs;
  float4 sd4 = *(const float4*)(sD + (size_t)node * 4);
  int j = lane & (OUT - 1);            // output index within node row
  int h = j / C;                       // head
  int slot0 = lane / OUT;
  float d0=0,d1=0,d2=0,d3=0;
  float acc = 0.f;

  for (int base = 0; base < deg; base += 64){
    int k = base + lane;
    float w0=0,w1=0,w2=0,w3=0; int s = 0;
    if (k < deg){
      s = srcs[rs + k];
      float4 ss = *(const float4*)(sS + (size_t)s * 4);
      float a0 = ss.x + sd4.x, a1 = ss.y + sd4.y, a2 = ss.z + sd4.z, a3 = ss.w + sd4.w;
      if (EDGE){
        float4 e4 = *(const float4*)(esc + (size_t)(rs + k) * 4);
        a0 += e4.x; a1 += e4.y; a2 += e4.z; a3 += e4.w;
      }
      w0 = expf(lrelu(a0)); w1 = expf(lrelu(a1));
      w2 = expf(lrelu(a2)); w3 = expf(lrelu(a3));
    }
    d0 += w0; d1 += w1; d2 += w2; d3 += w3;
    s_w[wv][lane] = make_float4(w0,w1,w2,w3);
    s_src[wv][lane] = s;
    WAVE_FENCE();
    int nvalid = min(deg - base, 64);
    int nit = (nvalid + EPI - 1) / EPI;
    for (int i = 0; i < nit; ++i){
      int slot = i * EPI + slot0;
      int src2 = s_src[wv][slot];
      float wgt = ((const float*)&s_w[wv][slot])[h];
      acc = fmaf(wgt, xh[(size_t)src2 * OUT + j], acc);
    }
    WAVE_FENCE();
  }

  // combine edge-slot copies of the output accumulators
  #pragma unroll
  for (int off = OUT; off < 64; off <<= 1) acc += __shfl_xor(acc, off, 64);
  // total denominator per head (all lanes get all 4)
  for (int off = 1; off < 64; off <<= 1){
    d0 += __shfl_xor(d0, off, 64); d1 += __shfl_xor(d1, off, 64);
    d2 += __shfl_xor(d2, off, 64); d3 += __shfl_xor(d3, off, 64);
  }
  float dsel = (h == 0) ? d0 : (h == 1) ? d1 : (h == 2) ? d2 : d3;
  float val = acc / (dsel + 1e-16f);

  if (MODE == 0){
    val += bias[j];
    val = elu1(val);
    if (lane < OUT) out[(size_t)node * OUT + j] = val;
  } else if (MODE == 1){
    val += __shfl_xor(val, 8, 64);
    val += __shfl_xor(val, 16, 64);
    val = val * 0.25f + bias[j & (C - 1)];
    val = elu1(val);
    if (lane < C) out[(size_t)node * C + j] = val;
  } else {
    val += __shfl_xor(val, 1, 64);
    val += __shfl_xor(val, 2, 64);
    val = val * 0.25f + bias[0];
    if (lane == 0) out[node] = val;
  }
}

// ---------------- launcher ----------------

extern "C" void kernel_launch(void* const* d_in, const int* in_sizes, int n_in,
                              void* d_out, int out_size, void* d_ws, size_t ws_size,
                              hipStream_t stream){
  const float* x     = (const float*)d_in[0];
  const float* eattr = (const float*)d_in[1];
  const int*   ei    = (const int*)d_in[2];
  const float* W1  = (const float*)d_in[3];
  const float* as1 = (const float*)d_in[4];
  const float* ad1 = (const float*)d_in[5];
  const float* We1 = (const float*)d_in[6];
  const float* ae1 = (const float*)d_in[7];
  const float* b1  = (const float*)d_in[8];
  const float* W2  = (const float*)d_in[9];
  const float* as2 = (const float*)d_in[10];
  const float* ad2 = (const float*)d_in[11];
  const float* b2  = (const float*)d_in[12];
  const float* W3  = (const float*)d_in[13];
  const float* as3 = (const float*)d_in[14];
  const float* ad3 = (const float*)d_in[15];
  const float* b3  = (const float*)d_in[16];

  const int N  = in_sizes[0] / 128;
  const int E  = in_sizes[2] / 2;
  const int EA = E + N;

  // float arrays first (16B-aligned; all counts are multiples of 4)
  float* fp = (float*)d_ws;
  float* esc = fp; fp += (size_t)EA * 4;
  float* xh  = fp; fp += (size_t)N * 32;
  float* sS  = fp; fp += (size_t)N * 4;
  float* sD  = fp; fp += (size_t)N * 4;
  float* h1  = fp; fp += (size_t)N * 32;
  float* h2  = fp; fp += (size_t)N * 8;
  float* wev = fp; fp += 32;
  int* ip = (int*)fp;
  int* cnt       = ip; ip += N;
  int* row_start = ip; ip += N + 1;
  int* cursor    = ip; ip += N;
  int* srcs      = ip; ip += EA;
  int* eid       = ip; ip += EA;

  const int B = 256;

  // ---- CSR build (self-loop first in each row) ----
  hipMemsetAsync(cnt, 0, (size_t)N * sizeof(int), stream);
  hist_kernel<<<cdiv(E, B), B, 0, stream>>>(ei, E, cnt);
  scan_kernel<<<1, 1024, 0, stream>>>(cnt, row_start, cursor, N);
  scatter_kernel<<<cdiv(E, B), B, 0, stream>>>(ei, E, cursor, srcs, eid);
  wevec_kernel<<<1, 32, 0, stream>>>(We1, ae1, wev);
  edge_prep_kernel<<<cdiv(N, 4), B, 0, stream>>>(row_start, eid, eattr, wev, srcs, esc, N);

  // ---- layer 1: 128 -> 4x8, concat, edge scores ----
  gemm_kernel<128,32><<<cdiv(N, 8), B, 0, stream>>>(x, W1, xh, N);
  score_kernel<32,8><<<cdiv(N * 4, B), B, 0, stream>>>(xh, as1, ad1, sS, sD, N);
  gather_kernel<8,0,true><<<cdiv(N, 4), B, 0, stream>>>(row_start, srcs, esc, sS, sD, xh, b1, h1, N);

  // ---- layer 2: 32 -> 4x8, mean heads ----
  gemm_kernel<32,32><<<cdiv(N, 8), B, 0, stream>>>(h1, W2, xh, N);
  score_kernel<32,8><<<cdiv(N * 4, B), B, 0, stream>>>(xh, as2, ad2, sS, sD, N);
  gather_kernel<8,1,false><<<cdiv(N, 4), B, 0, stream>>>(row_start, srcs, esc, sS, sD, xh, b2, h2, N);

  // ---- layer 3: 8 -> 4x1, mean heads ----
  gemm_kernel<8,4><<<cdiv(N, 64), B, 0, stream>>>(h2, W3, xh, N);
  score_kernel<4,1><<<cdiv(N * 4, B), B, 0, stream>>>(xh, as3, ad3, sS, sD, N);
  gather_kernel<1,2,false><<<cdiv(N, 4), B, 0, stream>>>(row_start, srcs, esc, sS, sD, xh, b3, (float*)d_out, N);
}

// Round 3
// 802.678 us; speedup vs baseline: 19.9268x; 1.0976x over previous
//
#include <hip/hip_runtime.h>
#include <cmath>

static inline int cdiv(long a, int b){ return (int)((a + b - 1) / b); }

__device__ __forceinline__ float lrelu(float x){ return x > 0.f ? x : 0.2f * x; }
__device__ __forceinline__ float elu1(float x){ return x > 0.f ? x : expm1f(x); }

// compiler-level fence: keep LDS writes (phase1) before LDS reads (phase2)
// within the same wave; HW DS pipe is in-order per wave.
#define WAVE_FENCE() do { asm volatile("" ::: "memory"); __builtin_amdgcn_sched_barrier(0); } while(0)

// ---------------- CSR build ----------------

__global__ void hist_kernel(const int* __restrict__ ei, int E, int* __restrict__ cnt){
  int e = blockIdx.x * blockDim.x + threadIdx.x;
  if (e < E) atomicAdd(&cnt[ei[E + e]], 1);
}

#define SCAN_B 1024
// block-local exclusive scan of cnt -> row_start (local), block totals -> partials
__global__ void scan_partial_kernel(const int* __restrict__ cnt, int* __restrict__ row_start,
                                    int* __restrict__ partials, int n){
  __shared__ int s[SCAN_B];
  int t = threadIdx.x, i = blockIdx.x * SCAN_B + t;
  int v = (i < n) ? cnt[i] : 0;
  s[t] = v; __syncthreads();
  #pragma unroll
  for (int off = 1; off < SCAN_B; off <<= 1){
    int u = (t >= off) ? s[t - off] : 0;
    __syncthreads();
    s[t] += u;
    __syncthreads();
  }
  if (i < n) row_start[i] = s[t] - v;
  if (t == SCAN_B - 1) partials[blockIdx.x] = s[t];
}

// single block: exclusive scan of partials (nb <= 256); also row_start[n] = total
__global__ void scan_tops_kernel(int* __restrict__ partials, int nb,
                                 int* __restrict__ row_start, int n, int total){
  __shared__ int s[256];
  int t = threadIdx.x;
  int v = (t < nb) ? partials[t] : 0;
  s[t] = v; __syncthreads();
  #pragma unroll
  for (int off = 1; off < 256; off <<= 1){
    int u = (t >= off) ? s[t - off] : 0;
    __syncthreads();
    s[t] += u;
    __syncthreads();
  }
  if (t < nb) partials[t] = s[t] - v;
  if (t == 0) row_start[n] = total;
}

__global__ void scan_add_kernel(const int* __restrict__ partials, int* __restrict__ row_start,
                                int* __restrict__ cursor, int n){
  int i = blockIdx.x * blockDim.x + threadIdx.x;
  if (i >= n) return;
  int v = row_start[i] + partials[i >> 10];
  row_start[i] = v;
  cursor[i] = v;
}

// one packed 8B record per edge: {src, eid}
__global__ void scatter_kernel(const int* __restrict__ ei, int E, int* __restrict__ cursor,
                               int2* __restrict__ recs){
  int e = blockIdx.x * blockDim.x + threadIdx.x;
  if (e >= E) return;
  int d = ei[E + e];
  int pos = atomicAdd(&cursor[d], 1);
  recs[pos] = make_int2(ei[e], e);
}

// wev[d*4+h] = sum_c We1[d, h*8+c] * a_e1[h,c]
__global__ void wevec_kernel(const float* __restrict__ We, const float* __restrict__ ae,
                             float* __restrict__ wev){
  int i = threadIdx.x;
  if (i >= 32) return;
  int d = i >> 2, h = i & 3;
  float acc = 0.f;
  #pragma unroll
  for (int c = 0; c < 8; ++c) acc = fmaf(We[d * 32 + h * 8 + c], ae[h * 8 + c], acc);
  wev[d * 4 + h] = acc;
}

// ---------------- fused node transform + attention pre-scores ----------------
// out[n,M] = A[n,K] @ W[K,M]; sS[n,4]/sD[n,4] = per-head dot with asrc/adst.
template<int K, int M, int C>
__global__ void gemm_score_kernel(const float* __restrict__ A, const float* __restrict__ W,
                                  const float* __restrict__ asrc, const float* __restrict__ adst,
                                  float* __restrict__ out, float* __restrict__ sS,
                                  float* __restrict__ sD, int n){
  __shared__ float Ws[K * M];
  __shared__ float s_as[M], s_ad[M];
  for (int i = threadIdx.x; i < K * M; i += blockDim.x) Ws[i] = W[i];
  if (threadIdx.x < M){ s_as[threadIdx.x] = asrc[threadIdx.x]; s_ad[threadIdx.x] = adst[threadIdx.x]; }
  __syncthreads();
  constexpr int ROWS = 256 / M;
  int row = blockIdx.x * ROWS + (int)threadIdx.x / M;
  int col = (int)threadIdx.x % M;
  if (row >= n) return;
  const float* a = A + (size_t)row * K;
  float acc = 0.f;
  #pragma unroll
  for (int k = 0; k < K; ++k) acc = fmaf(a[k], Ws[k * M + col], acc);
  out[(size_t)row * M + col] = acc;
  float ps = acc * s_as[col], pd = acc * s_ad[col];
  #pragma unroll
  for (int off = 1; off < C; off <<= 1){
    ps += __shfl_xor(ps, off, 64);
    pd += __shfl_xor(pd, off, 64);
  }
  if ((col & (C - 1)) == 0){
    int h = col / C;
    sS[(size_t)row * 4 + h] = ps;
    sD[(size_t)row * 4 + h] = pd;
  }
}

// ---------------- CSR gather-aggregate (no atomics, no amax, self-loop folded) ----
// MODE 0: concat heads + bias + ELU (layer1, OUT=32), EDGE scores from eattr
// MODE 1: mean heads + bias + ELU   (layer2, OUT=32 -> 8)
// MODE 2: mean heads + bias         (layer3, OUT=4  -> 1)
template<int C, int MODE, bool EDGE>
__global__ void gather_kernel(const int* __restrict__ row_start, const int2* __restrict__ recs,
                              const float* __restrict__ eattr, const float* __restrict__ wev,
                              const float* __restrict__ sS, const float* __restrict__ sD,
                              const float* __restrict__ xh, const float* __restrict__ bias,
                              float* __restrict__ out, int n){
  constexpr int OUT = 4 * C;
  constexpr int EPI = 64 / OUT;        // edges per phase-2 iteration
  __shared__ float4 s_w[4][64];
  __shared__ int    s_src[4][64];
  __shared__ float  s_wev[32];
  if (EDGE && threadIdx.x < 32) s_wev[threadIdx.x] = wev[threadIdx.x];
  __syncthreads();
  int wv = threadIdx.x >> 6, lane = threadIdx.x & 63;
  int node = blockIdx.x * 4 + wv;
  if (node >= n) return;
  int rs = row_start[node], deg = row_start[node + 1] - rs;
  float4 ss4 = *(const float4*)(sS + (size_t)node * 4);
  float4 sd4 = *(const float4*)(sD + (size_t)node * 4);
  int j = lane & (OUT - 1);            // output index within node row
  int h = j / C;                       // head
  int slot0 = lane / OUT;
  float d0 = 0, d1 = 0, d2 = 0, d3 = 0;
  float es0 = 0, es1 = 0, es2 = 0, es3 = 0;   // running sum of edge scores (for self-loop mean)
  float acc = 0.f;

  for (int base = 0; base < deg; base += 64){
    int k = base + lane;
    float w0 = 0, w1 = 0, w2 = 0, w3 = 0; int s = 0;
    if (k < deg){
      int2 rec = recs[rs + k];
      s = rec.x;
      float4 ss = *(const float4*)(sS + (size_t)s * 4);
      float a0 = ss.x + sd4.x, a1 = ss.y + sd4.y, a2 = ss.z + sd4.z, a3 = ss.w + sd4.w;
      if (EDGE){
        const float4* ea = (const float4*)(eattr + (size_t)rec.y * 8);
        float4 v0 = ea[0], v1 = ea[1];
        float av[8] = {v0.x, v0.y, v0.z, v0.w, v1.x, v1.y, v1.z, v1.w};
        float e0 = 0, e1 = 0, e2 = 0, e3 = 0;
        #pragma unroll
        for (int d2i = 0; d2i < 8; ++d2i){
          e0 = fmaf(av[d2i], s_wev[d2i * 4 + 0], e0);
          e1 = fmaf(av[d2i], s_wev[d2i * 4 + 1], e1);
          e2 = fmaf(av[d2i], s_wev[d2i * 4 + 2], e2);
          e3 = fmaf(av[d2i], s_wev[d2i * 4 + 3], e3);
        }
        a0 += e0; a1 += e1; a2 += e2; a3 += e3;
        es0 += e0; es1 += e1; es2 += e2; es3 += e3;
      }
      w0 = expf(lrelu(a0)); w1 = expf(lrelu(a1));
      w2 = expf(lrelu(a2)); w3 = expf(lrelu(a3));
    }
    d0 += w0; d1 += w1; d2 += w2; d3 += w3;
    s_w[wv][lane] = make_float4(w0, w1, w2, w3);
    s_src[wv][lane] = s;
    WAVE_FENCE();
    int nvalid = min(deg - base, 64);
    int nit = (nvalid + EPI - 1) / EPI;
    for (int i = 0; i < nit; ++i){
      int slot = i * EPI + slot0;
      int src2 = s_src[wv][slot];
      float wgt = ((const float*)&s_w[wv][slot])[h];
      acc = fmaf(wgt, xh[(size_t)src2 * OUT + j], acc);
    }
    WAVE_FENCE();
  }

  // combine edge-slot copies of the output accumulators
  #pragma unroll
  for (int off = OUT; off < 64; off <<= 1) acc += __shfl_xor(acc, off, 64);
  // total denominator per head (all lanes get all 4)
  #pragma unroll
  for (int off = 1; off < 64; off <<= 1){
    d0 += __shfl_xor(d0, off, 64); d1 += __shfl_xor(d1, off, 64);
    d2 += __shfl_xor(d2, off, 64); d3 += __shfl_xor(d3, off, 64);
  }
  // self-loop: alpha = sS[node]+sD[node] (+ mean edge score for layer 1)
  float se0 = 0, se1 = 0, se2 = 0, se3 = 0;
  if (EDGE){
    #pragma unroll
    for (int off = 1; off < 64; off <<= 1){
      es0 += __shfl_xor(es0, off, 64); es1 += __shfl_xor(es1, off, 64);
      es2 += __shfl_xor(es2, off, 64); es3 += __shfl_xor(es3, off, 64);
    }
    float inv = 1.f / fmaxf((float)deg, 1.f);
    se0 = es0 * inv; se1 = es1 * inv; se2 = es2 * inv; se3 = es3 * inv;
  }
  float ws0 = expf(lrelu(ss4.x + sd4.x + se0));
  float ws1 = expf(lrelu(ss4.y + sd4.y + se1));
  float ws2 = expf(lrelu(ss4.z + sd4.z + se2));
  float ws3 = expf(lrelu(ss4.w + sd4.w + se3));
  d0 += ws0; d1 += ws1; d2 += ws2; d3 += ws3;
  float wsel = (h == 0) ? ws0 : (h == 1) ? ws1 : (h == 2) ? ws2 : ws3;
  acc = fmaf(wsel, xh[(size_t)node * OUT + j], acc);
  float dsel = (h == 0) ? d0 : (h == 1) ? d1 : (h == 2) ? d2 : d3;
  float val = acc / (dsel + 1e-16f);

  if (MODE == 0){
    val += bias[j];
    val = elu1(val);
    if (lane < OUT) out[(size_t)node * OUT + j] = val;
  } else if (MODE == 1){
    val += __shfl_xor(val, 8, 64);
    val += __shfl_xor(val, 16, 64);
    val = val * 0.25f + bias[j & (C - 1)];
    val = elu1(val);
    if (lane < C) out[(size_t)node * C + j] = val;
  } else {
    val += __shfl_xor(val, 1, 64);
    val += __shfl_xor(val, 2, 64);
    val = val * 0.25f + bias[0];
    if (lane == 0) out[node] = val;
  }
}

// ---------------- launcher ----------------

extern "C" void kernel_launch(void* const* d_in, const int* in_sizes, int n_in,
                              void* d_out, int out_size, void* d_ws, size_t ws_size,
                              hipStream_t stream){
  const float* x     = (const float*)d_in[0];
  const float* eattr = (const float*)d_in[1];
  const int*   ei    = (const int*)d_in[2];
  const float* W1  = (const float*)d_in[3];
  const float* as1 = (const float*)d_in[4];
  const float* ad1 = (const float*)d_in[5];
  const float* We1 = (const float*)d_in[6];
  const float* ae1 = (const float*)d_in[7];
  const float* b1  = (const float*)d_in[8];
  const float* W2  = (const float*)d_in[9];
  const float* as2 = (const float*)d_in[10];
  const float* ad2 = (const float*)d_in[11];
  const float* b2  = (const float*)d_in[12];
  const float* W3  = (const float*)d_in[13];
  const float* as3 = (const float*)d_in[14];
  const float* ad3 = (const float*)d_in[15];
  const float* b3  = (const float*)d_in[16];

  const int N = in_sizes[0] / 128;
  const int E = in_sizes[2] / 2;

  float* fp = (float*)d_ws;
  float* xh  = fp; fp += (size_t)N * 32;
  float* sS  = fp; fp += (size_t)N * 4;
  float* sD  = fp; fp += (size_t)N * 4;
  float* h1  = fp; fp += (size_t)N * 32;
  float* h2  = fp; fp += (size_t)N * 8;
  float* wev = fp; fp += 32;
  int* ip = (int*)fp;
  int2* recs     = (int2*)ip; ip += (size_t)E * 2;
  int* cnt       = ip; ip += N;
  int* cursor    = ip; ip += N;
  int* partials  = ip; ip += 256;
  int* row_start = ip; ip += N + 1;

  const int B = 256;
  const int nb = cdiv(N, SCAN_B);

  // ---- CSR build ----
  hipMemsetAsync(cnt, 0, (size_t)N * sizeof(int), stream);
  hist_kernel<<<cdiv(E, B), B, 0, stream>>>(ei, E, cnt);
  scan_partial_kernel<<<nb, SCAN_B, 0, stream>>>(cnt, row_start, partials, N);
  scan_tops_kernel<<<1, 256, 0, stream>>>(partials, nb, row_start, N, E);
  scan_add_kernel<<<cdiv(N, B), B, 0, stream>>>(partials, row_start, cursor, N);
  scatter_kernel<<<cdiv(E, B), B, 0, stream>>>(ei, E, cursor, recs);
  wevec_kernel<<<1, 32, 0, stream>>>(We1, ae1, wev);

  // ---- layer 1: 128 -> 4x8, concat, edge scores ----
  gemm_score_kernel<128,32,8><<<cdiv(N, 8), B, 0, stream>>>(x, W1, as1, ad1, xh, sS, sD, N);
  gather_kernel<8,0,true><<<cdiv(N, 4), B, 0, stream>>>(row_start, recs, eattr, wev, sS, sD, xh, b1, h1, N);

  // ---- layer 2: 32 -> 4x8, mean heads ----
  gemm_score_kernel<32,32,8><<<cdiv(N, 8), B, 0, stream>>>(h1, W2, as2, ad2, xh, sS, sD, N);
  gather_kernel<8,1,false><<<cdiv(N, 4), B, 0, stream>>>(row_start, recs, eattr, wev, sS, sD, xh, b2, h2, N);

  // ---- layer 3: 8 -> 4x1, mean heads ----
  gemm_score_kernel<8,4,1><<<cdiv(N, 64), B, 0, stream>>>(h2, W3, as3, ad3, xh, sS, sD, N);
  gather_kernel<1,2,false><<<cdiv(N, 4), B, 0, stream>>>(row_start, recs, eattr, wev, sS, sD, xh, b3, (float*)d_out, N);
}

// Round 4
// 597.567 us; speedup vs baseline: 26.7666x; 1.3432x over previous
//
#include <hip/hip_runtime.h>
#include <cmath>

static inline int cdiv(long a, int b){ return (int)((a + b - 1) / b); }

__device__ __forceinline__ float lrelu(float x){ return x > 0.f ? x : 0.2f * x; }
__device__ __forceinline__ float elu1(float x){ return x > 0.f ? x : expm1f(x); }

// compiler-level fence: keep LDS writes (phase1) before LDS reads (phase2)
// within the same wave; HW DS pipe is in-order per wave.
#define WAVE_FENCE() do { asm volatile("" ::: "memory"); __builtin_amdgcn_sched_barrier(0); } while(0)

#define W_SHIFT 7                 // 128 nodes per bucket
#define NBMAX   1024              // LDS histogram size (>= nb)
#define EID_BITS 22               // E < 2^22
#define EID_MASK ((1 << EID_BITS) - 1)

// ---------------- CSR build (two-level binned scatter) ----------------

// fused node histogram + per-block LDS bucket histogram
__global__ void hist2_kernel(const int* __restrict__ ei, int E,
                             int* __restrict__ cnt, int* __restrict__ bcnt){
  __shared__ int s_b[NBMAX];
  for (int i = threadIdx.x; i < NBMAX; i += blockDim.x) s_b[i] = 0;
  __syncthreads();
  int stride = gridDim.x * blockDim.x;
  for (int e = blockIdx.x * blockDim.x + threadIdx.x; e < E; e += stride){
    int d = ei[E + e];
    atomicAdd(&cnt[d], 1);
    atomicAdd(&s_b[d >> W_SHIFT], 1);
  }
  __syncthreads();
  for (int i = threadIdx.x; i < NBMAX; i += blockDim.x)
    if (s_b[i]) atomicAdd(&bcnt[i], s_b[i]);
}

#define SCAN_B 1024
// block-local exclusive scan of cnt -> row_start (local), block totals -> partials
__global__ void scan_partial_kernel(const int* __restrict__ cnt, int* __restrict__ row_start,
                                    int* __restrict__ partials, int n){
  __shared__ int s[SCAN_B];
  int t = threadIdx.x, i = blockIdx.x * SCAN_B + t;
  int v = (i < n) ? cnt[i] : 0;
  s[t] = v; __syncthreads();
  #pragma unroll
  for (int off = 1; off < SCAN_B; off <<= 1){
    int u = (t >= off) ? s[t - off] : 0;
    __syncthreads();
    s[t] += u;
    __syncthreads();
  }
  if (i < n) row_start[i] = s[t] - v;
  if (t == SCAN_B - 1) partials[blockIdx.x] = s[t];
}

// single block: exclusive scan of partials (nb <= 256); also row_start[n] = total
__global__ void scan_tops_kernel(int* __restrict__ partials, int nb,
                                 int* __restrict__ row_start, int n, int total){
  __shared__ int s[256];
  int t = threadIdx.x;
  int v = (t < nb) ? partials[t] : 0;
  s[t] = v; __syncthreads();
  #pragma unroll
  for (int off = 1; off < 256; off <<= 1){
    int u = (t >= off) ? s[t - off] : 0;
    __syncthreads();
    s[t] += u;
    __syncthreads();
  }
  if (t < nb) partials[t] = s[t] - v;
  if (t == 0) row_start[n] = total;
}

__global__ void scan_add_kernel(const int* __restrict__ partials, int* __restrict__ row_start, int n){
  int i = blockIdx.x * blockDim.x + threadIdx.x;
  if (i < n) row_start[i] += partials[i >> 10];
}

// single block 1024-thread exclusive scan of bucket counts -> bstart, bcursor
__global__ void scan_buckets_kernel(const int* __restrict__ bcnt, int nb, int total,
                                    int* __restrict__ bstart, int* __restrict__ bcursor){
  __shared__ int s[1024];
  int t = threadIdx.x;
  int v = (t < nb) ? bcnt[t] : 0;
  s[t] = v; __syncthreads();
  #pragma unroll
  for (int off = 1; off < 1024; off <<= 1){
    int u = (t >= off) ? s[t - off] : 0;
    __syncthreads();
    s[t] += u;
    __syncthreads();
  }
  if (t < nb){ bstart[t] = s[t] - v; bcursor[t] = s[t] - v; }
  if (t == 0) bstart[nb] = total;
}

// block-aggregated multisplit: stage edges into bucket-contiguous regions
#define S3_CHUNK 8192
__global__ void multisplit_kernel(const int* __restrict__ ei, int E,
                                  int* __restrict__ bcursor, int2* __restrict__ staged){
  __shared__ int s_hist[NBMAX];
  __shared__ int s_base[NBMAX];
  int t = threadIdx.x;
  for (int i = t; i < NBMAX; i += 256) s_hist[i] = 0;
  __syncthreads();
  int lo = blockIdx.x * S3_CHUNK;
  int hi = min(lo + S3_CHUNK, E);
  for (int e = lo + t; e < hi; e += 256)
    atomicAdd(&s_hist[ei[E + e] >> W_SHIFT], 1);
  __syncthreads();
  for (int i = t; i < NBMAX; i += 256){
    int c = s_hist[i];
    s_base[i] = c ? atomicAdd(&bcursor[i], c) : 0;
    s_hist[i] = 0;
  }
  __syncthreads();
  for (int e = lo + t; e < hi; e += 256){
    int d = ei[E + e];
    int b = d >> W_SHIFT;
    int pos = s_base[b] + atomicAdd(&s_hist[b], 1);
    staged[pos] = make_int2(ei[e], e | ((d & ((1 << W_SHIFT) - 1)) << EID_BITS));
  }
}

// per-bucket scatter to final CSR slots; node cursors in LDS, output window L2-resident
__global__ void bucket_scatter_kernel(const int* __restrict__ bstart, const int2* __restrict__ staged,
                                      const int* __restrict__ row_start, int n,
                                      int2* __restrict__ recs){
  __shared__ int s_cur[1 << W_SHIFT];
  int b = blockIdx.x, t = threadIdx.x;
  int node0 = b << W_SHIFT;
  if (t < (1 << W_SHIFT)){
    int nd = node0 + t;
    s_cur[t] = (nd < n) ? row_start[nd] : 0;
  }
  __syncthreads();
  int lo = bstart[b], hi = bstart[b + 1];
  for (int i = lo + t; i < hi; i += 256){
    int2 r = staged[i];
    int dl = (unsigned)r.y >> EID_BITS;
    int pos = atomicAdd(&s_cur[dl], 1);
    recs[pos] = make_int2(r.x, r.y & EID_MASK);
  }
}

// wev[d*4+h] = sum_c We1[d, h*8+c] * a_e1[h,c]
__global__ void wevec_kernel(const float* __restrict__ We, const float* __restrict__ ae,
                             float* __restrict__ wev){
  int i = threadIdx.x;
  if (i >= 32) return;
  int d = i >> 2, h = i & 3;
  float acc = 0.f;
  #pragma unroll
  for (int c = 0; c < 8; ++c) acc = fmaf(We[d * 32 + h * 8 + c], ae[h * 8 + c], acc);
  wev[d * 4 + h] = acc;
}

// ---------------- fused node transform + attention pre-scores ----------------
template<int K, int M, int C>
__global__ void gemm_score_kernel(const float* __restrict__ A, const float* __restrict__ W,
                                  const float* __restrict__ asrc, const float* __restrict__ adst,
                                  float* __restrict__ out, float* __restrict__ sS,
                                  float* __restrict__ sD, int n){
  __shared__ float Ws[K * M];
  __shared__ float s_as[M], s_ad[M];
  for (int i = threadIdx.x; i < K * M; i += blockDim.x) Ws[i] = W[i];
  if (threadIdx.x < M){ s_as[threadIdx.x] = asrc[threadIdx.x]; s_ad[threadIdx.x] = adst[threadIdx.x]; }
  __syncthreads();
  constexpr int ROWS = 256 / M;
  int row = blockIdx.x * ROWS + (int)threadIdx.x / M;
  int col = (int)threadIdx.x % M;
  if (row >= n) return;
  const float* a = A + (size_t)row * K;
  float acc = 0.f;
  #pragma unroll
  for (int k = 0; k < K; ++k) acc = fmaf(a[k], Ws[k * M + col], acc);
  out[(size_t)row * M + col] = acc;
  float ps = acc * s_as[col], pd = acc * s_ad[col];
  #pragma unroll
  for (int off = 1; off < C; off <<= 1){
    ps += __shfl_xor(ps, off, 64);
    pd += __shfl_xor(pd, off, 64);
  }
  if ((col & (C - 1)) == 0){
    int h = col / C;
    sS[(size_t)row * 4 + h] = ps;
    sD[(size_t)row * 4 + h] = pd;
  }
}

// ---------------- CSR gather-aggregate ----------------
// MODE 0: concat heads + bias + ELU (layer1, OUT=32), EDGE scores from eattr
// MODE 1: mean heads + bias + ELU   (layer2)
// MODE 2: mean heads + bias         (layer3)
template<int C, int MODE, bool EDGE>
__global__ void gather_kernel(const int* __restrict__ row_start, const int2* __restrict__ recs,
                              const float* __restrict__ eattr, const float* __restrict__ wev,
                              const float* __restrict__ sS, const float* __restrict__ sD,
                              const float* __restrict__ xh, const float* __restrict__ bias,
                              float* __restrict__ out, int n){
  constexpr int OUT = 4 * C;
  constexpr int EPI = 64 / OUT;        // edges per phase-2 iteration
  __shared__ float4 s_w[4][64];
  __shared__ int    s_src[4][64];
  __shared__ float  s_wev[32];
  if (EDGE && threadIdx.x < 32) s_wev[threadIdx.x] = wev[threadIdx.x];
  __syncthreads();
  int wv = threadIdx.x >> 6, lane = threadIdx.x & 63;
  int node = blockIdx.x * 4 + wv;
  if (node >= n) return;
  int rs = row_start[node], deg = row_start[node + 1] - rs;
  float4 ss4 = *(const float4*)(sS + (size_t)node * 4);
  float4 sd4 = *(const float4*)(sD + (size_t)node * 4);
  int j = lane & (OUT - 1);
  int h = j / C;
  int slot0 = lane / OUT;
  float d0 = 0, d1 = 0, d2 = 0, d3 = 0;
  float es0 = 0, es1 = 0, es2 = 0, es3 = 0;
  float acc = 0.f;

  for (int base = 0; base < deg; base += 64){
    int k = base + lane;
    float w0 = 0, w1 = 0, w2 = 0, w3 = 0; int s = 0;
    if (k < deg){
      int2 rec = recs[rs + k];
      s = rec.x;
      float4 ss = *(const float4*)(sS + (size_t)s * 4);
      float a0 = ss.x + sd4.x, a1 = ss.y + sd4.y, a2 = ss.z + sd4.z, a3 = ss.w + sd4.w;
      if (EDGE){
        const float4* ea = (const float4*)(eattr + (size_t)rec.y * 8);
        float4 v0 = ea[0], v1 = ea[1];
        float av[8] = {v0.x, v0.y, v0.z, v0.w, v1.x, v1.y, v1.z, v1.w};
        float e0 = 0, e1 = 0, e2 = 0, e3 = 0;
        #pragma unroll
        for (int d2i = 0; d2i < 8; ++d2i){
          e0 = fmaf(av[d2i], s_wev[d2i * 4 + 0], e0);
          e1 = fmaf(av[d2i], s_wev[d2i * 4 + 1], e1);
          e2 = fmaf(av[d2i], s_wev[d2i * 4 + 2], e2);
          e3 = fmaf(av[d2i], s_wev[d2i * 4 + 3], e3);
        }
        a0 += e0; a1 += e1; a2 += e2; a3 += e3;
        es0 += e0; es1 += e1; es2 += e2; es3 += e3;
      }
      w0 = expf(lrelu(a0)); w1 = expf(lrelu(a1));
      w2 = expf(lrelu(a2)); w3 = expf(lrelu(a3));
    }
    d0 += w0; d1 += w1; d2 += w2; d3 += w3;
    s_w[wv][lane] = make_float4(w0, w1, w2, w3);
    s_src[wv][lane] = s;
    WAVE_FENCE();
    int nvalid = min(deg - base, 64);
    int nit = (nvalid + EPI - 1) / EPI;
    for (int i = 0; i < nit; ++i){
      int slot = i * EPI + slot0;
      int src2 = s_src[wv][slot];
      float wgt = ((const float*)&s_w[wv][slot])[h];
      acc = fmaf(wgt, xh[(size_t)src2 * OUT + j], acc);
    }
    WAVE_FENCE();
  }

  #pragma unroll
  for (int off = OUT; off < 64; off <<= 1) acc += __shfl_xor(acc, off, 64);
  #pragma unroll
  for (int off = 1; off < 64; off <<= 1){
    d0 += __shfl_xor(d0, off, 64); d1 += __shfl_xor(d1, off, 64);
    d2 += __shfl_xor(d2, off, 64); d3 += __shfl_xor(d3, off, 64);
  }
  // self-loop: alpha = sS[node]+sD[node] (+ mean edge score for layer 1)
  float se0 = 0, se1 = 0, se2 = 0, se3 = 0;
  if (EDGE){
    #pragma unroll
    for (int off = 1; off < 64; off <<= 1){
      es0 += __shfl_xor(es0, off, 64); es1 += __shfl_xor(es1, off, 64);
      es2 += __shfl_xor(es2, off, 64); es3 += __shfl_xor(es3, off, 64);
    }
    float inv = 1.f / fmaxf((float)deg, 1.f);
    se0 = es0 * inv; se1 = es1 * inv; se2 = es2 * inv; se3 = es3 * inv;
  }
  float ws0 = expf(lrelu(ss4.x + sd4.x + se0));
  float ws1 = expf(lrelu(ss4.y + sd4.y + se1));
  float ws2 = expf(lrelu(ss4.z + sd4.z + se2));
  float ws3 = expf(lrelu(ss4.w + sd4.w + se3));
  d0 += ws0; d1 += ws1; d2 += ws2; d3 += ws3;
  float wsel = (h == 0) ? ws0 : (h == 1) ? ws1 : (h == 2) ? ws2 : ws3;
  acc = fmaf(wsel, xh[(size_t)node * OUT + j], acc);
  float dsel = (h == 0) ? d0 : (h == 1) ? d1 : (h == 2) ? d2 : d3;
  float val = acc / (dsel + 1e-16f);

  if (MODE == 0){
    val += bias[j];
    val = elu1(val);
    if (lane < OUT) out[(size_t)node * OUT + j] = val;
  } else if (MODE == 1){
    val += __shfl_xor(val, 8, 64);
    val += __shfl_xor(val, 16, 64);
    val = val * 0.25f + bias[j & (C - 1)];
    val = elu1(val);
    if (lane < C) out[(size_t)node * C + j] = val;
  } else {
    val += __shfl_xor(val, 1, 64);
    val += __shfl_xor(val, 2, 64);
    val = val * 0.25f + bias[0];
    if (lane == 0) out[node] = val;
  }
}

// ---------------- launcher ----------------

extern "C" void kernel_launch(void* const* d_in, const int* in_sizes, int n_in,
                              void* d_out, int out_size, void* d_ws, size_t ws_size,
                              hipStream_t stream){
  const float* x     = (const float*)d_in[0];
  const float* eattr = (const float*)d_in[1];
  const int*   ei    = (const int*)d_in[2];
  const float* W1  = (const float*)d_in[3];
  const float* as1 = (const float*)d_in[4];
  const float* ad1 = (const float*)d_in[5];
  const float* We1 = (const float*)d_in[6];
  const float* ae1 = (const float*)d_in[7];
  const float* b1  = (const float*)d_in[8];
  const float* W2  = (const float*)d_in[9];
  const float* as2 = (const float*)d_in[10];
  const float* ad2 = (const float*)d_in[11];
  const float* b2  = (const float*)d_in[12];
  const float* W3  = (const float*)d_in[13];
  const float* as3 = (const float*)d_in[14];
  const float* ad3 = (const float*)d_in[15];
  const float* b3  = (const float*)d_in[16];

  const int N = in_sizes[0] / 128;
  const int E = in_sizes[2] / 2;
  const int nb_buckets = (N + (1 << W_SHIFT) - 1) >> W_SHIFT;   // 782 for N=100000

  float* fp = (float*)d_ws;
  float* xh  = fp; fp += (size_t)N * 32;
  float* sS  = fp; fp += (size_t)N * 4;
  float* sD  = fp; fp += (size_t)N * 4;
  float* h1  = fp; fp += (size_t)N * 32;
  float* h2  = fp; fp += (size_t)N * 8;
  float* wev = fp; fp += 32;
  // staged aliases the float region: fully consumed by bucket_scatter before
  // any float array is written (stream-ordered).
  int2* staged = (int2*)d_ws;                     // E * 8 bytes <= xh+sS+sD+h1
  int* ip = (int*)fp;
  int2* recs     = (int2*)ip; ip += (size_t)E * 2;
  int* cnt       = ip; ip += N;                   // cnt .. bcnt contiguous for memset
  int* bcnt      = ip; ip += NBMAX;
  int* partials  = ip; ip += 256;
  int* row_start = ip; ip += N + 1;
  int* bstart    = ip; ip += NBMAX + 1;
  int* bcursor   = ip; ip += NBMAX;

  const int B = 256;
  const int nb_scan = cdiv(N, SCAN_B);

  // ---- CSR build: hist -> scans -> multisplit -> bucket scatter ----
  hipMemsetAsync(cnt, 0, (size_t)(N + NBMAX) * sizeof(int), stream);
  hist2_kernel<<<512, B, 0, stream>>>(ei, E, cnt, bcnt);
  scan_partial_kernel<<<nb_scan, SCAN_B, 0, stream>>>(cnt, row_start, partials, N);
  scan_tops_kernel<<<1, 256, 0, stream>>>(partials, nb_scan, row_start, N, E);
  scan_add_kernel<<<cdiv(N, B), B, 0, stream>>>(partials, row_start, N);
  scan_buckets_kernel<<<1, 1024, 0, stream>>>(bcnt, nb_buckets, E, bstart, bcursor);
  multisplit_kernel<<<cdiv(E, S3_CHUNK), B, 0, stream>>>(ei, E, bcursor, staged);
  bucket_scatter_kernel<<<nb_buckets, B, 0, stream>>>(bstart, staged, row_start, N, recs);
  wevec_kernel<<<1, 32, 0, stream>>>(We1, ae1, wev);

  // ---- layer 1: 128 -> 4x8, concat, edge scores ----
  gemm_score_kernel<128,32,8><<<cdiv(N, 8), B, 0, stream>>>(x, W1, as1, ad1, xh, sS, sD, N);
  gather_kernel<8,0,true><<<cdiv(N, 4), B, 0, stream>>>(row_start, recs, eattr, wev, sS, sD, xh, b1, h1, N);

  // ---- layer 2: 32 -> 4x8, mean heads ----
  gemm_score_kernel<32,32,8><<<cdiv(N, 8), B, 0, stream>>>(h1, W2, as2, ad2, xh, sS, sD, N);
  gather_kernel<8,1,false><<<cdiv(N, 4), B, 0, stream>>>(row_start, recs, eattr, wev, sS, sD, xh, b2, h2, N);

  // ---- layer 3: 8 -> 4x1, mean heads ----
  gemm_score_kernel<8,4,1><<<cdiv(N, 64), B, 0, stream>>>(h2, W3, as3, ad3, xh, sS, sD, N);
  gather_kernel<1,2,false><<<cdiv(N, 4), B, 0, stream>>>(row_start, recs, eattr, wev, sS, sD, xh, b3, (float*)d_out, N);
}